// Round 6
// baseline (288.393 us; speedup 1.0000x reference)
//
#include <hip/hip_runtime.h>
#include <stdint.h>

#define SEQ 2048
#define DIM 1024
#define NB 4
#define MTOT (NB*SEQ)
#define QKVN (3*DIM)

typedef __attribute__((ext_vector_type(8))) short short8;
typedef __attribute__((ext_vector_type(4))) float f32x4;

__device__ __forceinline__ unsigned short f2b(float f) {
    union { float f; unsigned int u; } v; v.f = f;
    return (unsigned short)((v.u + 0x7FFFu + ((v.u >> 16) & 1u)) >> 16);
}

__device__ __forceinline__ void gload_lds16(const unsigned short* g, unsigned short* l) {
    __builtin_amdgcn_global_load_lds(
        (const __attribute__((address_space(1))) void*)g,
        (__attribute__((address_space(3))) void*)l, 16, 0, 0);
}

// inline-asm LDS read: invisible to backend waitcnt insertion; dependency on the
// LDS-DMA is managed ONLY by our counted vmcnt/lgkmcnt ledger.
__device__ __forceinline__ short8 ds128(unsigned addr) {
    short8 r;
    asm volatile("ds_read_b128 %0, %1" : "=v"(r) : "v"(addr));
    return r;
}

#define FENCE_BARRIER do { asm volatile("" ::: "memory"); \
    __builtin_amdgcn_s_barrier(); asm volatile("" ::: "memory"); } while (0)

__device__ __forceinline__ int xcd_swz(int bid, int nwg) {
    if (nwg & 7) return bid;
    return (bid & 7) * (nwg >> 3) + (bid >> 3);
}

// ---------------- small memory-shape kernels ----------------

__global__ __launch_bounds__(256)
void cast_kernel(const float* __restrict__ in, unsigned short* __restrict__ out, int nchunk) {
    int i = blockIdx.x * 256 + threadIdx.x;
    if (i >= nchunk) return;
    float4 a = ((const float4*)in)[i*2];
    float4 b = ((const float4*)in)[i*2+1];
    union { unsigned short u[8]; uint4 v; } r;
    r.u[0]=f2b(a.x); r.u[1]=f2b(a.y); r.u[2]=f2b(a.z); r.u[3]=f2b(a.w);
    r.u[4]=f2b(b.x); r.u[5]=f2b(b.y); r.u[6]=f2b(b.z); r.u[7]=f2b(b.w);
    ((uint4*)out)[i] = r.v;
}

__global__ __launch_bounds__(256)
void transpose_cast_f32(const float* __restrict__ in, unsigned short* __restrict__ out, int R, int C) {
    __shared__ unsigned short tile[64][66];
    int tpc = C >> 6;
    int tr = (blockIdx.x / tpc) << 6;
    int tc = (blockIdx.x % tpc) << 6;
    int t = threadIdx.x;
    #pragma unroll
    for (int i = 0; i < 16; i++) {
        int idx = t + i*256;
        int r = idx >> 6, c = idx & 63;
        tile[r][c] = f2b(in[(size_t)(tr + r)*C + tc + c]);
    }
    __syncthreads();
    #pragma unroll
    for (int i = 0; i < 16; i++) {
        int idx = t + i*256;
        int r = idx >> 6, c = idx & 63;
        out[(size_t)(tc + r)*R + tr + c] = tile[c][r];
    }
}

__global__ __launch_bounds__(256)
void transpose_b16(const unsigned short* __restrict__ in0, size_t sIn, int ldin,
                   unsigned short* __restrict__ out0, size_t sOut, int ldout, int tpc) {
    const unsigned short* in = in0 + sIn * blockIdx.y;
    unsigned short* out = out0 + sOut * blockIdx.y;
    __shared__ unsigned short tile[64][66];
    int tr = ((int)blockIdx.x / tpc) << 6;
    int tc = ((int)blockIdx.x % tpc) << 6;
    int t = threadIdx.x;
    #pragma unroll
    for (int i = 0; i < 16; i++) {
        int idx = t + i*256;
        int r = idx >> 6, c = idx & 63;
        tile[r][c] = in[(size_t)(tr + r)*ldin + tc + c];
    }
    __syncthreads();
    #pragma unroll
    for (int i = 0; i < 16; i++) {
        int idx = t + i*256;
        int r = idx >> 6, c = idx & 63;
        out[(size_t)(tc + r)*ldout + tr + c] = tile[c][r];
    }
}

__global__ __launch_bounds__(256)
void bias_concat(const float* __restrict__ bq, const float* __restrict__ bk,
                 const float* __restrict__ bv, float* __restrict__ o) {
    int i = blockIdx.x*256 + threadIdx.x;
    float v = (i < DIM) ? bq[i] : ((i < 2*DIM) ? bk[i-DIM] : bv[i-2*DIM]);
    o[i] = v;
}

// -------- 256x256 8-phase GEMM, pipelined fragments (reads overlap MFMA) --------
// 8 waves (2M x 4N), BK=64, 2 K-tiles/iter. One barrier per phase.
// Block p = { reads for MFMA_{p+1} ; sched_barrier ; MFMA_p (no wait — operands
// read last phase) ; lgkmcnt(0) ; stage slot ; [vmcnt(6) at b3/b7] ; barrier }.
// B-quads read once per tile and carried in regs (fb0 has E/O parity sets).
// Stage slots: b1 E2.Ah0 | b2 E2.Bh1 | b3 E2.Ah1 | b4 E2.Bh0 |
//              b5 O2.Ah0 | b6 O2.Bh1 | b7 O2.Ah1 | b8 O2.Bh0.
// vmcnt(6) at b3 end publishes tile O (drains its 4 halves); at b7 publishes E2.

__device__ __forceinline__ void stage1(const unsigned short* __restrict__ Xb, int ldx,
                                       unsigned short* dstBase, int h, int k0,
                                       int tid, int wid) {
    int srow = tid >> 3;
    int scol = ((tid & 7) ^ (srow & 7)) << 3;     // inverse XOR-swizzle on global src
    const unsigned short* g = Xb + (size_t)(h*128 + srow)*ldx + k0 + scol;
    unsigned short* d = dstBase + h*8192 + wid*512;
    gload_lds16(g, d);
    gload_lds16(g + (size_t)64*ldx, d + 4096);
}

#define RD_A(DST, BUF, QM) do { _Pragma("unroll") for (int mf = 0; mf < 4; ++mf) { \
    DST[mf][0] = ds128(As0 + (BUF)*32768u + (QM)*16384u + aRow + mf*2048u + c0);   \
    DST[mf][1] = ds128(As0 + (BUF)*32768u + (QM)*16384u + aRow + mf*2048u + c1); } } while (0)

#define RD_B(DST, BUF, QN) do { _Pragma("unroll") for (int nf = 0; nf < 2; ++nf) { \
    DST[nf][0] = ds128(Bs0 + (BUF)*32768u + (QN)*16384u + bRow + nf*2048u + c0);   \
    DST[nf][1] = ds128(Bs0 + (BUF)*32768u + (QN)*16384u + bRow + nf*2048u + c1); } } while (0)

#define MMA16(FA, FB, QM, QN) do { \
    __builtin_amdgcn_sched_barrier(0); \
    __builtin_amdgcn_s_setprio(1); \
    _Pragma("unroll") for (int mf = 0; mf < 4; ++mf) \
      _Pragma("unroll") for (int nf = 0; nf < 2; ++nf) \
        _Pragma("unroll") for (int ks = 0; ks < 2; ++ks) \
          acc[QM][QN][mf][nf] = __builtin_amdgcn_mfma_f32_16x16x32_bf16( \
              FA[mf][ks], FB[nf][ks], acc[QM][QN][mf][nf], 0, 0, 0); \
    __builtin_amdgcn_s_setprio(0); \
    asm volatile("s_waitcnt lgkmcnt(0)" ::: "memory"); \
    __builtin_amdgcn_sched_barrier(0); \
} while (0)

template<int MODE>   // 0: bf16(acc+bias[col]) ; 1: f32(acc)
__global__ __launch_bounds__(512, 2)
void gemm8p(const unsigned short* __restrict__ A, int lda, size_t sA,
            const unsigned short* __restrict__ Bt, int ldb, size_t sB,
            const float* __restrict__ bias,
            void* __restrict__ Cout, int ldc, size_t sC,
            int N, int K)
{
    __shared__ __align__(16) unsigned short As[2][16384];
    __shared__ __align__(16) unsigned short Bs[2][16384];
    int nbn = N >> 8;
    int bid = xcd_swz((int)blockIdx.x, (int)gridDim.x);
    int bm = bid / nbn, bn = bid % nbn;
    int bz = blockIdx.y;
    int tid = threadIdx.x;
    int lane = tid & 63;
    int wid  = tid >> 6;
    int wm = (wid >> 2) & 1;          // 2 waves in M
    int wn = wid & 3;                 // 4 waves in N
    int rlo = lane & 15;
    int shi = lane >> 4;

    unsigned As0 = (unsigned)(uintptr_t)&As[0][0];
    unsigned Bs0 = (unsigned)(uintptr_t)&Bs[0][0];
    unsigned c0 = (unsigned)(((shi     ^ rlo) & 7) * 16);   // ks=0 swizzled 16B slot
    unsigned c1 = (unsigned)((((4+shi) ^ rlo) & 7) * 16);   // ks=1
    unsigned aRow = (unsigned)((wm*64 + rlo) * 128);        // byte offset within half
    unsigned bRow = (unsigned)((wn*32 + rlo) * 128);

    f32x4 acc[2][2][4][2];
    #pragma unroll
    for (int a = 0; a < 2; a++)
        #pragma unroll
        for (int b = 0; b < 2; b++)
            #pragma unroll
            for (int c = 0; c < 4; c++)
                #pragma unroll
                for (int d = 0; d < 2; d++)
                    acc[a][b][c][d] = (f32x4){0.f,0.f,0.f,0.f};

    const unsigned short* Ab = A + sA*bz + (size_t)(bm*256)*lda;
    const unsigned short* Bb = Bt + sB*bz + (size_t)(bn*256)*ldb;

    // frag sets: A alternates faA/faB; B-quads read once/tile and carried.
    short8 faA[4][2], faB[4][2];      // A quad 0 / quad 1 (per-tile alternating)
    short8 fb0X[2][2];                // B quad0, even tiles
    short8 fb0Y[2][2];                // B quad0, odd tiles
    short8 fb1[2][2];                 // B quad1 (per-tile, short lifetime)

    // prologue: stage tile E (4 halves) + tile O (4 halves) = 16 loads;
    // vmcnt(6) drains E(8) + O.Ah0(2), leaves 6.
    stage1(Ab, lda, &As[0][0], 0, 0,  tid, wid);
    stage1(Bb, ldb, &Bs[0][0], 0, 0,  tid, wid);
    stage1(Ab, lda, &As[0][0], 1, 0,  tid, wid);
    stage1(Bb, ldb, &Bs[0][0], 1, 0,  tid, wid);
    stage1(Ab, lda, &As[1][0], 0, 64, tid, wid);
    stage1(Bb, ldb, &Bs[1][0], 1, 64, tid, wid);
    stage1(Ab, lda, &As[1][0], 1, 64, tid, wid);
    stage1(Bb, ldb, &Bs[1][0], 0, 64, tid, wid);
    __builtin_amdgcn_sched_barrier(0);
    asm volatile("s_waitcnt vmcnt(6)" ::: "memory");
    FENCE_BARRIER;
    // prologue reads: operands for b1's MFMA (E quad (0,0))
    RD_A(faA, 0, 0); RD_B(fb0X, 0, 0);
    __builtin_amdgcn_sched_barrier(0);
    asm volatile("s_waitcnt lgkmcnt(0)" ::: "memory");
    __builtin_amdgcn_sched_barrier(0);
    FENCE_BARRIER;   // separates prologue reads from b1's stage (anti-WAR across waves)

    int nt = K >> 6;          // even, >= 4
    int nit = nt >> 1;

    for (int it = 0; it < nit; ++it) {
        int kE2 = (2*it + 2 < nt) ? (2*it + 2) << 6 : 0;   // dummy k keeps ledger uniform
        int kO2 = (2*it + 3 < nt) ? (2*it + 3) << 6 : 0;

        // b1: MFMA E(0,0); reads B1E; stage E2.Ah0
        RD_B(fb1, 0, 1);
        MMA16(faA, fb0X, 0, 0);
        stage1(Ab, lda, &As[0][0], 0, kE2, tid, wid);
        FENCE_BARRIER;
        // b2: MFMA E(0,1); reads A1E; stage E2.Bh1
        RD_A(faB, 0, 1);
        MMA16(faA, fb1, 0, 1);
        stage1(Bb, ldb, &Bs[0][0], 1, kE2, tid, wid);
        FENCE_BARRIER;
        // b3: MFMA E(1,1); no reads; stage E2.Ah1; publish tile O
        MMA16(faB, fb1, 1, 1);
        stage1(Ab, lda, &As[0][0], 1, kE2, tid, wid);
        __builtin_amdgcn_sched_barrier(0);
        asm volatile("s_waitcnt vmcnt(6)" ::: "memory");
        FENCE_BARRIER;
        // b4: MFMA E(1,0); reads A0O + B0O; stage E2.Bh0
        RD_A(faA, 1, 0); RD_B(fb0Y, 1, 0);
        MMA16(faB, fb0X, 1, 0);
        stage1(Bb, ldb, &Bs[0][0], 0, kE2, tid, wid);
        FENCE_BARRIER;
        // b5: MFMA O(0,0); reads B1O; stage O2.Ah0
        RD_B(fb1, 1, 1);
        MMA16(faA, fb0Y, 0, 0);
        stage1(Ab, lda, &As[1][0], 0, kO2, tid, wid);
        FENCE_BARRIER;
        // b6: MFMA O(0,1); reads A1O; stage O2.Bh1
        RD_A(faB, 1, 1);
        MMA16(faA, fb1, 0, 1);
        stage1(Bb, ldb, &Bs[1][0], 1, kO2, tid, wid);
        FENCE_BARRIER;
        // b7: MFMA O(1,1); no reads; stage O2.Ah1; publish tile E2
        MMA16(faB, fb1, 1, 1);
        stage1(Ab, lda, &As[1][0], 1, kO2, tid, wid);
        __builtin_amdgcn_sched_barrier(0);
        asm volatile("s_waitcnt vmcnt(6)" ::: "memory");
        FENCE_BARRIER;
        // b8: MFMA O(1,0); reads A0E2 + B0E2 (next iter's b1 operands); stage O2.Bh0
        RD_A(faA, 0, 0); RD_B(fb0X, 0, 0);
        MMA16(faB, fb0Y, 1, 0);
        stage1(Bb, ldb, &Bs[1][0], 0, kO2, tid, wid);
        FENCE_BARRIER;
    }

    // drain dummy-stage DMAs before LDS deallocation at wave exit
    asm volatile("s_waitcnt vmcnt(0)" ::: "memory");

    int r0 = shi << 2;
    unsigned short* Cu = (unsigned short*)Cout + sC*bz;
    float* Cf = (float*)Cout + sC*bz;
    #pragma unroll
    for (int qm = 0; qm < 2; ++qm)
        #pragma unroll
        for (int qn = 0; qn < 2; ++qn)
            #pragma unroll
            for (int mf = 0; mf < 4; ++mf)
                #pragma unroll
                for (int nf = 0; nf < 2; ++nf) {
                    int col = bn*256 + qn*128 + wn*32 + nf*16 + rlo;
                    float badd = (MODE == 0) ? bias[col] : 0.f;
                    #pragma unroll
                    for (int r = 0; r < 4; ++r) {
                        int row = bm*256 + qm*128 + wm*64 + mf*16 + r0 + r;
                        float v = acc[qm][qn][mf][nf][r];
                        if (MODE == 0) Cu[(size_t)row*ldc + col] = f2b(v + badd);
                        else           Cf[(size_t)row*ldc + col] = v;
                    }
                }
}

// ---------------- m97-style 128x128 GEMM (PV: keeps high occupancy) ----------------
__global__ __launch_bounds__(256, 2)
void gemm_nt_pv(const unsigned short* __restrict__ A, int lda, size_t sA,
                const unsigned short* __restrict__ Bt, int ldb, size_t sB,
                float* __restrict__ Cout, int ldc, size_t sC,
                int N, int K)
{
    __shared__ __align__(16) unsigned short As[128][64];
    __shared__ __align__(16) unsigned short Bs[128][64];
    int nbn = N >> 7;
    int bid = xcd_swz((int)blockIdx.x, (int)gridDim.x);
    int bm = bid / nbn;
    int bn = bid % nbn;
    int bz = blockIdx.y;
    int tid = threadIdx.x;
    int lane = tid & 63;
    int wid  = tid >> 6;
    int wm = (wid >> 1) * 64, wn = (wid & 1) * 64;
    int lr = lane & 15;
    int lk = (lane >> 4) * 8;
    int srow = lane >> 3;
    int scol = (lane & 7) * 8;

    f32x4 acc[4][4];
    #pragma unroll
    for (int i = 0; i < 4; i++)
        #pragma unroll
        for (int j = 0; j < 4; j++) acc[i][j] = (f32x4){0.f,0.f,0.f,0.f};

    const unsigned short* Ab = A + sA*bz + (size_t)(bm*128)*lda;
    const unsigned short* Bb = Bt + sB*bz + (size_t)(bn*128)*ldb;

    for (int k0 = 0; k0 < K; k0 += 64) {
        #pragma unroll
        for (int r = 0; r < 4; r++) {
            int rowg = r*32 + wid*8;
            gload_lds16(Ab + (size_t)(rowg + srow)*lda + k0 + scol, &As[rowg][0]);
            gload_lds16(Bb + (size_t)(rowg + srow)*ldb + k0 + scol, &Bs[rowg][0]);
        }
        __syncthreads();
        #pragma unroll
        for (int ks = 0; ks < 2; ks++) {
            short8 af[4], bfr[4];
            #pragma unroll
            for (int mf = 0; mf < 4; mf++)
                af[mf] = *(const short8*)&As[wm + mf*16 + lr][ks*32 + lk];
            #pragma unroll
            for (int nf = 0; nf < 4; nf++)
                bfr[nf] = *(const short8*)&Bs[wn + nf*16 + lr][ks*32 + lk];
            #pragma unroll
            for (int mf = 0; mf < 4; mf++)
                #pragma unroll
                for (int nf = 0; nf < 4; nf++)
                    acc[mf][nf] = __builtin_amdgcn_mfma_f32_16x16x32_bf16(af[mf], bfr[nf], acc[mf][nf], 0, 0, 0);
        }
        __syncthreads();
    }

    int r0 = (lane >> 4) << 2;
    float* Cf = Cout + sC*bz;
    #pragma unroll
    for (int mf = 0; mf < 4; mf++)
        #pragma unroll
        for (int nf = 0; nf < 4; nf++) {
            int col = bn*128 + wn + nf*16 + lr;
            #pragma unroll
            for (int r = 0; r < 4; r++) {
                int row = bm*128 + wm + mf*16 + r0 + r;
                Cf[(size_t)row*ldc + col] = acc[mf][nf][r];
            }
        }
}

// row softmax over 2048 fp32 scores (scaled by scl); writes bf16 probs in-place
__global__ __launch_bounds__(256)
void softmax_kernel(float* __restrict__ S, float scl) {
    int row = blockIdx.x;
    float* srow = S + (size_t)row * SEQ;
    int t = threadIdx.x;
    float4 v0 = ((const float4*)srow)[t*2];
    float4 v1 = ((const float4*)srow)[t*2+1];
    float x[8] = {v0.x*scl,v0.y*scl,v0.z*scl,v0.w*scl,v1.x*scl,v1.y*scl,v1.z*scl,v1.w*scl};
    float m = fmaxf(fmaxf(fmaxf(x[0],x[1]),fmaxf(x[2],x[3])),
                    fmaxf(fmaxf(x[4],x[5]),fmaxf(x[6],x[7])));
    #pragma unroll
    for (int off = 32; off; off >>= 1) m = fmaxf(m, __shfl_xor(m, off));
    __shared__ float redm[4], reds[4];
    int w = t >> 6;
    if ((t & 63) == 0) redm[w] = m;
    __syncthreads();
    m = fmaxf(fmaxf(redm[0], redm[1]), fmaxf(redm[2], redm[3]));
    float e[8]; float s = 0.f;
    #pragma unroll
    for (int i = 0; i < 8; i++) { e[i] = __expf(x[i] - m); s += e[i]; }
    #pragma unroll
    for (int off = 32; off; off >>= 1) s += __shfl_xor(s, off);
    if ((t & 63) == 0) reds[w] = s;
    __syncthreads();
    float inv = 1.0f / (reds[0]+reds[1]+reds[2]+reds[3]);
    union { unsigned short u[8]; uint4 v; } r;
    #pragma unroll
    for (int i = 0; i < 8; i++) r.u[i] = f2b(e[i] * inv);
    ((uint4*)srow)[t] = r.v;
}

extern "C" void kernel_launch(void* const* d_in, const int* in_sizes, int n_in,
                              void* d_out, int out_size, void* d_ws, size_t ws_size,
                              hipStream_t stream)
{
    (void)in_sizes; (void)n_in; (void)out_size;
    const float* x  = (const float*)d_in[0];
    const float* Wq = (const float*)d_in[1];
    const float* bq = (const float*)d_in[2];
    const float* Wk = (const float*)d_in[3];
    const float* bk = (const float*)d_in[4];
    const float* Wv = (const float*)d_in[5];
    const float* bv = (const float*)d_in[6];
    float* out = (float*)d_out;

    unsigned short* qkv = (unsigned short*)d_ws;                    // [8192][3072]
    unsigned short* vt  = qkv + (size_t)MTOT*QKVN;                  // [4][1024][2048]
    float* biasc = (float*)(vt + (size_t)NB*DIM*SEQ);               // [3072]
    char* ovl = (char*)biasc + 65536;
    unsigned short* xb    = (unsigned short*)ovl;                   // [8192][1024]
    unsigned short* wqkvt = xb + (size_t)MTOT*DIM;                  // [3072][1024]
    float* scores = (float*)ovl;                                    // [bpp][2048][2048]

    size_t base = (size_t)MTOT*QKVN*2 + (size_t)NB*DIM*SEQ*2 + 65536;
    int bpp = 1;
    if (base + 4*(size_t)SEQ*SEQ*4 <= ws_size) bpp = 4;
    else if (base + 2*(size_t)SEQ*SEQ*4 <= ws_size) bpp = 2;

    cast_kernel<<<MTOT*DIM/8/256, 256, 0, stream>>>(x, xb, MTOT*DIM/8);
    transpose_cast_f32<<<256, 256, 0, stream>>>(Wq, wqkvt,             DIM, DIM);
    transpose_cast_f32<<<256, 256, 0, stream>>>(Wk, wqkvt + DIM*DIM,   DIM, DIM);
    transpose_cast_f32<<<256, 256, 0, stream>>>(Wv, wqkvt + 2*DIM*DIM, DIM, DIM);
    bias_concat<<<QKVN/256, 256, 0, stream>>>(bq, bk, bv, biasc);

    // fused QKV projection (pipelined 8-phase 256^2): [8192,1024] @ [3072,1024]^T
    gemm8p<0><<<dim3((MTOT/256)*(QKVN/256)), 512, 0, stream>>>(
        xb, DIM, 0, wqkvt, DIM, 0, biasc, qkv, QKVN, 0, QKVN, DIM);

    transpose_b16<<<dim3((SEQ/64)*(DIM/64), NB), 256, 0, stream>>>(
        qkv + 2*DIM, (size_t)SEQ*QKVN, QKVN, vt, (size_t)DIM*SEQ, SEQ, DIM/64);

    const float scl = 1.0f / 32.0f;   // 1/sqrt(1024), folded into softmax
    for (int p = 0; p < NB; p += bpp) {
        const unsigned short* qp = qkv + (size_t)p*SEQ*QKVN;
        gemm8p<1><<<dim3((SEQ/256)*(SEQ/256), bpp), 512, 0, stream>>>(
            qp,       QKVN, (size_t)SEQ*QKVN,
            qp + DIM, QKVN, (size_t)SEQ*QKVN,
            nullptr, scores, SEQ, (size_t)SEQ*SEQ, SEQ, DIM);
        softmax_kernel<<<bpp*SEQ, 256, 0, stream>>>(scores, scl);
        gemm_nt_pv<<<dim3((SEQ/128)*(DIM/128), bpp), 256, 0, stream>>>(
            (const unsigned short*)scores, 2*SEQ, (size_t)SEQ*2*SEQ,
            vt + (size_t)p*DIM*SEQ,        SEQ,   (size_t)DIM*SEQ,
            out + (size_t)p*SEQ*DIM, DIM, (size_t)SEQ*DIM, DIM, SEQ);
    }
}

// Round 7
// 192.864 us; speedup vs baseline: 1.4953x; 1.4953x over previous
//
#include <hip/hip_runtime.h>
#include <stdint.h>

#define SEQ 2048
#define DIM 1024
#define NB 4
#define MTOT (NB*SEQ)
#define QKVN (3*DIM)

typedef __attribute__((ext_vector_type(8))) short short8;
typedef __attribute__((ext_vector_type(4))) float f32x4;

__device__ __forceinline__ unsigned short f2b(float f) {
    union { float f; unsigned int u; } v; v.f = f;
    return (unsigned short)((v.u + 0x7FFFu + ((v.u >> 16) & 1u)) >> 16);
}

__device__ __forceinline__ void gload_lds16(const unsigned short* g, unsigned short* l) {
    __builtin_amdgcn_global_load_lds(
        (const __attribute__((address_space(1))) void*)g,
        (__attribute__((address_space(3))) void*)l, 16, 0, 0);
}

// inline-asm LDS read: invisible to backend waitcnt insertion; dependency on the
// LDS-DMA is managed ONLY by our counted vmcnt/lgkmcnt ledger.
__device__ __forceinline__ short8 ds128(unsigned addr) {
    short8 r;
    asm volatile("ds_read_b128 %0, %1" : "=v"(r) : "v"(addr));
    return r;
}

#define FENCE_BARRIER do { asm volatile("" ::: "memory"); \
    __builtin_amdgcn_s_barrier(); asm volatile("" ::: "memory"); } while (0)

__device__ __forceinline__ int xcd_swz(int bid, int nwg) {
    if (nwg & 7) return bid;
    return (bid & 7) * (nwg >> 3) + (bid >> 3);
}

// ---------------- small memory-shape kernels ----------------

__global__ __launch_bounds__(256)
void cast_kernel(const float* __restrict__ in, unsigned short* __restrict__ out, int nchunk) {
    int i = blockIdx.x * 256 + threadIdx.x;
    if (i >= nchunk) return;
    float4 a = ((const float4*)in)[i*2];
    float4 b = ((const float4*)in)[i*2+1];
    union { unsigned short u[8]; uint4 v; } r;
    r.u[0]=f2b(a.x); r.u[1]=f2b(a.y); r.u[2]=f2b(a.z); r.u[3]=f2b(a.w);
    r.u[4]=f2b(b.x); r.u[5]=f2b(b.y); r.u[6]=f2b(b.z); r.u[7]=f2b(b.w);
    ((uint4*)out)[i] = r.v;
}

__global__ __launch_bounds__(256)
void transpose_cast_f32(const float* __restrict__ in, unsigned short* __restrict__ out, int R, int C) {
    __shared__ unsigned short tile[64][66];
    int tpc = C >> 6;
    int tr = (blockIdx.x / tpc) << 6;
    int tc = (blockIdx.x % tpc) << 6;
    int t = threadIdx.x;
    #pragma unroll
    for (int i = 0; i < 16; i++) {
        int idx = t + i*256;
        int r = idx >> 6, c = idx & 63;
        tile[r][c] = f2b(in[(size_t)(tr + r)*C + tc + c]);
    }
    __syncthreads();
    #pragma unroll
    for (int i = 0; i < 16; i++) {
        int idx = t + i*256;
        int r = idx >> 6, c = idx & 63;
        out[(size_t)(tc + r)*R + tr + c] = tile[c][r];
    }
}

__global__ __launch_bounds__(256)
void transpose_b16(const unsigned short* __restrict__ in0, size_t sIn, int ldin,
                   unsigned short* __restrict__ out0, size_t sOut, int ldout, int tpc) {
    const unsigned short* in = in0 + sIn * blockIdx.y;
    unsigned short* out = out0 + sOut * blockIdx.y;
    __shared__ unsigned short tile[64][66];
    int tr = ((int)blockIdx.x / tpc) << 6;
    int tc = ((int)blockIdx.x % tpc) << 6;
    int t = threadIdx.x;
    #pragma unroll
    for (int i = 0; i < 16; i++) {
        int idx = t + i*256;
        int r = idx >> 6, c = idx & 63;
        tile[r][c] = in[(size_t)(tr + r)*ldin + tc + c];
    }
    __syncthreads();
    #pragma unroll
    for (int i = 0; i < 16; i++) {
        int idx = t + i*256;
        int r = idx >> 6, c = idx & 63;
        out[(size_t)(tc + r)*ldout + tr + c] = tile[c][r];
    }
}

__global__ __launch_bounds__(256)
void bias_concat(const float* __restrict__ bq, const float* __restrict__ bk,
                 const float* __restrict__ bv, float* __restrict__ o) {
    int i = blockIdx.x*256 + threadIdx.x;
    float v = (i < DIM) ? bq[i] : ((i < 2*DIM) ? bk[i-DIM] : bv[i-2*DIM]);
    o[i] = v;
}

// -------- 256x256 8-phase GEMM, m201-faithful: reads HOISTED pre-barrier --------
// 8 waves (2M x 4N), BK=64, 2 K-tiles/iter. Phase = { ds-reads (this phase's
// operands) ; stage slot ; [lgkmcnt(8) pace on 12-read phases] ; [vmcnt(6) at
// p4/p8] ; barrier ; lgkmcnt(0) ; setprio ; 16 MFMA ; setprio ; barrier }.
// Reads hide under barrier-arrival skew; zero extra frag registers vs round 5.
// Stage slots: p1 tO.Bh0 | p2 E2.Ah0 | p3 E2.Bh1 | p4 E2.Ah1 | p5 E2.Bh0 |
//              p6 O2.Ah0 | p7 O2.Bh1 | p8 O2.Ah1.  Publish: tO @p4, tE2 @p8.
// Hazards: every read's data published >=2 barriers before issue; every stage's
// target half last-read completed before the preceding MFMA barrier (verified).

__device__ __forceinline__ void stage1(const unsigned short* __restrict__ Xb, int ldx,
                                       unsigned short* dstBase, int h, int k0,
                                       int tid, int wid) {
    int srow = tid >> 3;
    int scol = ((tid & 7) ^ (srow & 7)) << 3;     // inverse XOR-swizzle on global src
    const unsigned short* g = Xb + (size_t)(h*128 + srow)*ldx + k0 + scol;
    unsigned short* d = dstBase + h*8192 + wid*512;
    gload_lds16(g, d);
    gload_lds16(g + (size_t)64*ldx, d + 4096);
}

#define RD_A(BUF, QM) do { _Pragma("unroll") for (int mf = 0; mf < 4; ++mf) { \
    fa[mf][0] = ds128(As0 + (BUF)*32768u + (QM)*16384u + aRow + mf*2048u + c0); \
    fa[mf][1] = ds128(As0 + (BUF)*32768u + (QM)*16384u + aRow + mf*2048u + c1); } } while (0)

#define RD_B(BUF, QN) do { _Pragma("unroll") for (int nf = 0; nf < 2; ++nf) { \
    fb[nf][0] = ds128(Bs0 + (BUF)*32768u + (QN)*16384u + bRow + nf*2048u + c0); \
    fb[nf][1] = ds128(Bs0 + (BUF)*32768u + (QN)*16384u + bRow + nf*2048u + c1); } } while (0)

#define MMA_PH(QM, QN) do { \
    asm volatile("s_waitcnt lgkmcnt(0)" ::: "memory"); \
    __builtin_amdgcn_sched_barrier(0); \
    __builtin_amdgcn_s_setprio(1); \
    _Pragma("unroll") for (int mf = 0; mf < 4; ++mf) \
      _Pragma("unroll") for (int nf = 0; nf < 2; ++nf) \
        _Pragma("unroll") for (int ks = 0; ks < 2; ++ks) \
          acc[QM][QN][mf][nf] = __builtin_amdgcn_mfma_f32_16x16x32_bf16( \
              fa[mf][ks], fb[nf][ks], acc[QM][QN][mf][nf], 0, 0, 0); \
    __builtin_amdgcn_s_setprio(0); \
} while (0)

template<int MODE>   // 0: bf16(acc+bias[col]) ; 1: f32(acc)
__global__ __launch_bounds__(512, 2)
void gemm8p(const unsigned short* __restrict__ A, int lda, size_t sA,
            const unsigned short* __restrict__ Bt, int ldb, size_t sB,
            const float* __restrict__ bias,
            void* __restrict__ Cout, int ldc, size_t sC,
            int N, int K)
{
    __shared__ __align__(16) unsigned short As[2][16384];
    __shared__ __align__(16) unsigned short Bs[2][16384];
    int nbn = N >> 8;
    int bid = xcd_swz((int)blockIdx.x, (int)gridDim.x);
    int bm = bid / nbn, bn = bid % nbn;
    int bz = blockIdx.y;
    int tid = threadIdx.x;
    int lane = tid & 63;
    int wid  = tid >> 6;
    int wm = (wid >> 2) & 1;          // 2 waves in M
    int wn = wid & 3;                 // 4 waves in N
    int rlo = lane & 15;
    int shi = lane >> 4;

    unsigned As0 = (unsigned)(uintptr_t)&As[0][0];
    unsigned Bs0 = (unsigned)(uintptr_t)&Bs[0][0];
    unsigned c0 = (unsigned)(((shi     ^ rlo) & 7) * 16);   // ks=0 swizzled 16B slot
    unsigned c1 = (unsigned)((((4+shi) ^ rlo) & 7) * 16);   // ks=1
    unsigned aRow = (unsigned)((wm*64 + rlo) * 128);        // byte offset within half
    unsigned bRow = (unsigned)((wn*32 + rlo) * 128);

    f32x4 acc[2][2][4][2];
    #pragma unroll
    for (int a = 0; a < 2; a++)
        #pragma unroll
        for (int b = 0; b < 2; b++)
            #pragma unroll
            for (int c = 0; c < 4; c++)
                #pragma unroll
                for (int d = 0; d < 2; d++)
                    acc[a][b][c][d] = (f32x4){0.f,0.f,0.f,0.f};

    const unsigned short* Ab = A + sA*bz + (size_t)(bm*256)*lda;
    const unsigned short* Bb = Bt + sB*bz + (size_t)(bn*256)*ldb;

    // prologue: tile E all 4 halves + tile O {Ah0, Bh1, Ah1} = 14 loads;
    // vmcnt(6) drains E, leaves O's 3 halves in flight.
    stage1(Ab, lda, &As[0][0], 0, 0,  tid, wid);
    stage1(Bb, ldb, &Bs[0][0], 0, 0,  tid, wid);
    stage1(Ab, lda, &As[0][0], 1, 0,  tid, wid);
    stage1(Bb, ldb, &Bs[0][0], 1, 0,  tid, wid);
    stage1(Ab, lda, &As[1][0], 0, 64, tid, wid);
    stage1(Bb, ldb, &Bs[1][0], 1, 64, tid, wid);
    stage1(Ab, lda, &As[1][0], 1, 64, tid, wid);
    __builtin_amdgcn_sched_barrier(0);
    asm volatile("s_waitcnt vmcnt(6)" ::: "memory");
    FENCE_BARRIER;

    short8 fa[4][2], fb[2][2];
    int nt = K >> 6;          // even, >= 4
    int nit = nt >> 1;

    for (int it = 0; it < nit; ++it) {
        int kO  = (2*it + 1) << 6;
        int kE2 = (2*it + 2 < nt) ? (2*it + 2) << 6 : 0;   // dummy k keeps ledger uniform
        int kO2 = (2*it + 3 < nt) ? (2*it + 3) << 6 : 0;

        // p1: reads E(0,0) [12]; stage tO.Bh0; pace; barrier; MFMA E(0,0)
        RD_A(0, 0); RD_B(0, 0);
        stage1(Bb, ldb, &Bs[1][0], 0, kO, tid, wid);
        asm volatile("s_waitcnt lgkmcnt(8)" ::: "memory");
        FENCE_BARRIER; MMA_PH(0, 0); FENCE_BARRIER;
        // p2: reads B1E [4]; stage E2.Ah0; barrier; MFMA E(0,1)
        RD_B(0, 1);
        stage1(Ab, lda, &As[0][0], 0, kE2, tid, wid);
        FENCE_BARRIER; MMA_PH(0, 1); FENCE_BARRIER;
        // p3: reads A1E [8]; stage E2.Bh1; barrier; MFMA E(1,1)
        RD_A(0, 1);
        stage1(Bb, ldb, &Bs[0][0], 1, kE2, tid, wid);
        FENCE_BARRIER; MMA_PH(1, 1); FENCE_BARRIER;
        // p4: reads B0E [4]; stage E2.Ah1; publish tile O; barrier; MFMA E(1,0)
        RD_B(0, 0);
        stage1(Ab, lda, &As[0][0], 1, kE2, tid, wid);
        __builtin_amdgcn_sched_barrier(0);
        asm volatile("s_waitcnt vmcnt(6)" ::: "memory");
        FENCE_BARRIER; MMA_PH(1, 0); FENCE_BARRIER;
        // p5: reads O(0,0) [12]; stage E2.Bh0; pace; barrier; MFMA O(0,0)
        RD_A(1, 0); RD_B(1, 0);
        stage1(Bb, ldb, &Bs[0][0], 0, kE2, tid, wid);
        asm volatile("s_waitcnt lgkmcnt(8)" ::: "memory");
        FENCE_BARRIER; MMA_PH(0, 0); FENCE_BARRIER;
        // p6: reads B1O [4]; stage O2.Ah0; barrier; MFMA O(0,1)
        RD_B(1, 1);
        stage1(Ab, lda, &As[1][0], 0, kO2, tid, wid);
        FENCE_BARRIER; MMA_PH(0, 1); FENCE_BARRIER;
        // p7: reads A1O [8]; stage O2.Bh1; barrier; MFMA O(1,1)
        RD_A(1, 1);
        stage1(Bb, ldb, &Bs[1][0], 1, kO2, tid, wid);
        FENCE_BARRIER; MMA_PH(1, 1); FENCE_BARRIER;
        // p8: reads B0O [4]; stage O2.Ah1; publish tile E2; barrier; MFMA O(1,0)
        RD_B(1, 0);
        stage1(Ab, lda, &As[1][0], 1, kO2, tid, wid);
        __builtin_amdgcn_sched_barrier(0);
        asm volatile("s_waitcnt vmcnt(6)" ::: "memory");
        FENCE_BARRIER; MMA_PH(1, 0); FENCE_BARRIER;
    }

    // drain dummy-stage DMAs before LDS deallocation at wave exit
    asm volatile("s_waitcnt vmcnt(0)" ::: "memory");

    int r0 = shi << 2;
    unsigned short* Cu = (unsigned short*)Cout + sC*bz;
    float* Cf = (float*)Cout + sC*bz;
    #pragma unroll
    for (int qm = 0; qm < 2; ++qm)
        #pragma unroll
        for (int qn = 0; qn < 2; ++qn)
            #pragma unroll
            for (int mf = 0; mf < 4; ++mf)
                #pragma unroll
                for (int nf = 0; nf < 2; ++nf) {
                    int col = bn*256 + qn*128 + wn*32 + nf*16 + rlo;
                    float badd = (MODE == 0) ? bias[col] : 0.f;
                    #pragma unroll
                    for (int r = 0; r < 4; ++r) {
                        int row = bm*256 + qm*128 + wm*64 + mf*16 + r0 + r;
                        float v = acc[qm][qn][mf][nf][r];
                        if (MODE == 0) Cu[(size_t)row*ldc + col] = f2b(v + badd);
                        else           Cf[(size_t)row*ldc + col] = v;
                    }
                }
}

// ---------------- m97-style 128x128 GEMM (PV: keeps high occupancy) ----------------
__global__ __launch_bounds__(256, 2)
void gemm_nt_pv(const unsigned short* __restrict__ A, int lda, size_t sA,
                const unsigned short* __restrict__ Bt, int ldb, size_t sB,
                float* __restrict__ Cout, int ldc, size_t sC,
                int N, int K)
{
    __shared__ __align__(16) unsigned short As[128][64];
    __shared__ __align__(16) unsigned short Bs[128][64];
    int nbn = N >> 7;
    int bid = xcd_swz((int)blockIdx.x, (int)gridDim.x);
    int bm = bid / nbn;
    int bn = bid % nbn;
    int bz = blockIdx.y;
    int tid = threadIdx.x;
    int lane = tid & 63;
    int wid  = tid >> 6;
    int wm = (wid >> 1) * 64, wn = (wid & 1) * 64;
    int lr = lane & 15;
    int lk = (lane >> 4) * 8;
    int srow = lane >> 3;
    int scol = (lane & 7) * 8;

    f32x4 acc[4][4];
    #pragma unroll
    for (int i = 0; i < 4; i++)
        #pragma unroll
        for (int j = 0; j < 4; j++) acc[i][j] = (f32x4){0.f,0.f,0.f,0.f};

    const unsigned short* Ab = A + sA*bz + (size_t)(bm*128)*lda;
    const unsigned short* Bb = Bt + sB*bz + (size_t)(bn*128)*ldb;

    for (int k0 = 0; k0 < K; k0 += 64) {
        #pragma unroll
        for (int r = 0; r < 4; r++) {
            int rowg = r*32 + wid*8;
            gload_lds16(Ab + (size_t)(rowg + srow)*lda + k0 + scol, &As[rowg][0]);
            gload_lds16(Bb + (size_t)(rowg + srow)*ldb + k0 + scol, &Bs[rowg][0]);
        }
        __syncthreads();
        #pragma unroll
        for (int ks = 0; ks < 2; ks++) {
            short8 af[4], bfr[4];
            #pragma unroll
            for (int mf = 0; mf < 4; mf++)
                af[mf] = *(const short8*)&As[wm + mf*16 + lr][ks*32 + lk];
            #pragma unroll
            for (int nf = 0; nf < 4; nf++)
                bfr[nf] = *(const short8*)&Bs[wn + nf*16 + lr][ks*32 + lk];
            #pragma unroll
            for (int mf = 0; mf < 4; mf++)
                #pragma unroll
                for (int nf = 0; nf < 4; nf++)
                    acc[mf][nf] = __builtin_amdgcn_mfma_f32_16x16x32_bf16(af[mf], bfr[nf], acc[mf][nf], 0, 0, 0);
        }
        __syncthreads();
    }

    int r0 = (lane >> 4) << 2;
    float* Cf = Cout + sC*bz;
    #pragma unroll
    for (int mf = 0; mf < 4; mf++)
        #pragma unroll
        for (int nf = 0; nf < 4; nf++) {
            int col = bn*128 + wn + nf*16 + lr;
            #pragma unroll
            for (int r = 0; r < 4; r++) {
                int row = bm*128 + wm + mf*16 + r0 + r;
                Cf[(size_t)row*ldc + col] = acc[mf][nf][r];
            }
        }
}

// row softmax over 2048 fp32 scores (scaled by scl); writes bf16 probs in-place
__global__ __launch_bounds__(256)
void softmax_kernel(float* __restrict__ S, float scl) {
    int row = blockIdx.x;
    float* srow = S + (size_t)row * SEQ;
    int t = threadIdx.x;
    float4 v0 = ((const float4*)srow)[t*2];
    float4 v1 = ((const float4*)srow)[t*2+1];
    float x[8] = {v0.x*scl,v0.y*scl,v0.z*scl,v0.w*scl,v1.x*scl,v1.y*scl,v1.z*scl,v1.w*scl};
    float m = fmaxf(fmaxf(fmaxf(x[0],x[1]),fmaxf(x[2],x[3])),
                    fmaxf(fmaxf(x[4],x[5]),fmaxf(x[6],x[7])));
    #pragma unroll
    for (int off = 32; off; off >>= 1) m = fmaxf(m, __shfl_xor(m, off));
    __shared__ float redm[4], reds[4];
    int w = t >> 6;
    if ((t & 63) == 0) redm[w] = m;
    __syncthreads();
    m = fmaxf(fmaxf(redm[0], redm[1]), fmaxf(redm[2], redm[3]));
    float e[8]; float s = 0.f;
    #pragma unroll
    for (int i = 0; i < 8; i++) { e[i] = __expf(x[i] - m); s += e[i]; }
    #pragma unroll
    for (int off = 32; off; off >>= 1) s += __shfl_xor(s, off);
    if ((t & 63) == 0) reds[w] = s;
    __syncthreads();
    float inv = 1.0f / (reds[0]+reds[1]+reds[2]+reds[3]);
    union { unsigned short u[8]; uint4 v; } r;
    #pragma unroll
    for (int i = 0; i < 8; i++) r.u[i] = f2b(e[i] * inv);
    ((uint4*)srow)[t] = r.v;
}

extern "C" void kernel_launch(void* const* d_in, const int* in_sizes, int n_in,
                              void* d_out, int out_size, void* d_ws, size_t ws_size,
                              hipStream_t stream)
{
    (void)in_sizes; (void)n_in; (void)out_size;
    const float* x  = (const float*)d_in[0];
    const float* Wq = (const float*)d_in[1];
    const float* bq = (const float*)d_in[2];
    const float* Wk = (const float*)d_in[3];
    const float* bk = (const float*)d_in[4];
    const float* Wv = (const float*)d_in[5];
    const float* bv = (const float*)d_in[6];
    float* out = (float*)d_out;

    unsigned short* qkv = (unsigned short*)d_ws;                    // [8192][3072]
    unsigned short* vt  = qkv + (size_t)MTOT*QKVN;                  // [4][1024][2048]
    float* biasc = (float*)(vt + (size_t)NB*DIM*SEQ);               // [3072]
    char* ovl = (char*)biasc + 65536;
    unsigned short* xb    = (unsigned short*)ovl;                   // [8192][1024]
    unsigned short* wqkvt = xb + (size_t)MTOT*DIM;                  // [3072][1024]
    float* scores = (float*)ovl;                                    // [bpp][2048][2048]

    size_t base = (size_t)MTOT*QKVN*2 + (size_t)NB*DIM*SEQ*2 + 65536;
    int bpp = 1;
    if (base + 4*(size_t)SEQ*SEQ*4 <= ws_size) bpp = 4;
    else if (base + 2*(size_t)SEQ*SEQ*4 <= ws_size) bpp = 2;

    cast_kernel<<<MTOT*DIM/8/256, 256, 0, stream>>>(x, xb, MTOT*DIM/8);
    transpose_cast_f32<<<256, 256, 0, stream>>>(Wq, wqkvt,             DIM, DIM);
    transpose_cast_f32<<<256, 256, 0, stream>>>(Wk, wqkvt + DIM*DIM,   DIM, DIM);
    transpose_cast_f32<<<256, 256, 0, stream>>>(Wv, wqkvt + 2*DIM*DIM, DIM, DIM);
    bias_concat<<<QKVN/256, 256, 0, stream>>>(bq, bk, bv, biasc);

    // fused QKV projection (8-phase 256^2, hoisted reads): [8192,1024] @ [3072,1024]^T
    gemm8p<0><<<dim3((MTOT/256)*(QKVN/256)), 512, 0, stream>>>(
        xb, DIM, 0, wqkvt, DIM, 0, biasc, qkv, QKVN, 0, QKVN, DIM);

    transpose_b16<<<dim3((SEQ/64)*(DIM/64), NB), 256, 0, stream>>>(
        qkv + 2*DIM, (size_t)SEQ*QKVN, QKVN, vt, (size_t)DIM*SEQ, SEQ, DIM/64);

    const float scl = 1.0f / 32.0f;   // 1/sqrt(1024), folded into softmax
    for (int p = 0; p < NB; p += bpp) {
        const unsigned short* qp = qkv + (size_t)p*SEQ*QKVN;
        gemm8p<1><<<dim3((SEQ/256)*(SEQ/256), bpp), 512, 0, stream>>>(
            qp,       QKVN, (size_t)SEQ*QKVN,
            qp + DIM, QKVN, (size_t)SEQ*QKVN,
            nullptr, scores, SEQ, (size_t)SEQ*SEQ, SEQ, DIM);
        softmax_kernel<<<bpp*SEQ, 256, 0, stream>>>(scores, scl);
        gemm_nt_pv<<<dim3((SEQ/128)*(DIM/128), bpp), 256, 0, stream>>>(
            (const unsigned short*)scores, 2*SEQ, (size_t)SEQ*2*SEQ,
            vt + (size_t)p*DIM*SEQ,        SEQ,   (size_t)DIM*SEQ,
            out + (size_t)p*SEQ*DIM, DIM, (size_t)SEQ*DIM, DIM, SEQ);
    }
}

// Round 8
// 189.769 us; speedup vs baseline: 1.5197x; 1.0163x over previous
//
#include <hip/hip_runtime.h>
#include <stdint.h>

#define SEQ 2048
#define DIM 1024
#define NB 4
#define MTOT (NB*SEQ)
#define QKVN (3*DIM)

typedef __attribute__((ext_vector_type(8))) short short8;
typedef __attribute__((ext_vector_type(4))) float f32x4;

__device__ __forceinline__ unsigned short f2b(float f) {
    union { float f; unsigned int u; } v; v.f = f;
    return (unsigned short)((v.u + 0x7FFFu + ((v.u >> 16) & 1u)) >> 16);
}

__device__ __forceinline__ void gload_lds16(const unsigned short* g, unsigned short* l) {
    __builtin_amdgcn_global_load_lds(
        (const __attribute__((address_space(1))) void*)g,
        (__attribute__((address_space(3))) void*)l, 16, 0, 0);
}

// inline-asm LDS read: invisible to backend waitcnt insertion; dependency on the
// LDS-DMA is managed ONLY by our counted vmcnt/lgkmcnt ledger.
__device__ __forceinline__ short8 ds128(unsigned addr) {
    short8 r;
    asm volatile("ds_read_b128 %0, %1" : "=v"(r) : "v"(addr));
    return r;
}

#define FENCE_BARRIER do { asm volatile("" ::: "memory"); \
    __builtin_amdgcn_s_barrier(); asm volatile("" ::: "memory"); } while (0)

__device__ __forceinline__ int xcd_swz(int bid, int nwg) {
    if (nwg & 7) return bid;
    return (bid & 7) * (nwg >> 3) + (bid >> 3);
}

// ---------------- small memory-shape kernels ----------------

__global__ __launch_bounds__(256)
void cast_kernel(const float* __restrict__ in, unsigned short* __restrict__ out, int nchunk) {
    int i = blockIdx.x * 256 + threadIdx.x;
    if (i >= nchunk) return;
    float4 a = ((const float4*)in)[i*2];
    float4 b = ((const float4*)in)[i*2+1];
    union { unsigned short u[8]; uint4 v; } r;
    r.u[0]=f2b(a.x); r.u[1]=f2b(a.y); r.u[2]=f2b(a.z); r.u[3]=f2b(a.w);
    r.u[4]=f2b(b.x); r.u[5]=f2b(b.y); r.u[6]=f2b(b.z); r.u[7]=f2b(b.w);
    ((uint4*)out)[i] = r.v;
}

__global__ __launch_bounds__(256)
void transpose_cast_f32(const float* __restrict__ in, unsigned short* __restrict__ out, int R, int C) {
    __shared__ unsigned short tile[64][66];
    int tpc = C >> 6;
    int tr = (blockIdx.x / tpc) << 6;
    int tc = (blockIdx.x % tpc) << 6;
    int t = threadIdx.x;
    #pragma unroll
    for (int i = 0; i < 16; i++) {
        int idx = t + i*256;
        int r = idx >> 6, c = idx & 63;
        tile[r][c] = f2b(in[(size_t)(tr + r)*C + tc + c]);
    }
    __syncthreads();
    #pragma unroll
    for (int i = 0; i < 16; i++) {
        int idx = t + i*256;
        int r = idx >> 6, c = idx & 63;
        out[(size_t)(tc + r)*R + tr + c] = tile[c][r];
    }
}

__global__ __launch_bounds__(256)
void transpose_b16(const unsigned short* __restrict__ in0, size_t sIn, int ldin,
                   unsigned short* __restrict__ out0, size_t sOut, int ldout, int tpc) {
    const unsigned short* in = in0 + sIn * blockIdx.y;
    unsigned short* out = out0 + sOut * blockIdx.y;
    __shared__ unsigned short tile[64][66];
    int tr = ((int)blockIdx.x / tpc) << 6;
    int tc = ((int)blockIdx.x % tpc) << 6;
    int t = threadIdx.x;
    #pragma unroll
    for (int i = 0; i < 16; i++) {
        int idx = t + i*256;
        int r = idx >> 6, c = idx & 63;
        tile[r][c] = in[(size_t)(tr + r)*ldin + tc + c];
    }
    __syncthreads();
    #pragma unroll
    for (int i = 0; i < 16; i++) {
        int idx = t + i*256;
        int r = idx >> 6, c = idx & 63;
        out[(size_t)(tc + r)*ldout + tr + c] = tile[c][r];
    }
}

__global__ __launch_bounds__(256)
void bias_concat(const float* __restrict__ bq, const float* __restrict__ bk,
                 const float* __restrict__ bv, float* __restrict__ o) {
    int i = blockIdx.x*256 + threadIdx.x;
    float v = (i < DIM) ? bq[i] : ((i < 2*DIM) ? bk[i-DIM] : bv[i-2*DIM]);
    o[i] = v;
}

// -------- 128x256 4-phase pipelined GEMM (exact-grid tiles) --------
// 8 waves (2M x 4N), BK=64, 2 K-tiles/iter (E=buf0, O=buf1). Per-wave 64x64,
// acc = 16 f32x4 (64 AGPR). Per phase: one qn-quadrant (128 cols) x one K-step
// = 16 MFMA. A-frags read once per K-tile (phase qn0) and held across qn1.
// LDS 96KB: As[2][128x64] 32KB + Bs[2][256x64] 64KB. XOR-swizzled via
// pre-swizzled global source (stage) + swizzled ds_read addr.
// Stage slots: p1 O.Bh1 | p2 E2.A + E2.Bh0, vmcnt(4) (publish O) |
//              p3 E2.Bh1 | p4 O2.A + O2.Bh0, vmcnt(4) (publish E2).
// Hazards: B-half h == qn-quadrant h; each staged half's last reader finished
// >=1 barrier before the stage issues (A@qn0-phase, Bh0@qn0, Bh1@qn1). Ledger:
// prologue 10 loads -> vmcnt(4); steady-state 8 in flight at publishes.

__device__ __forceinline__ void stage1(const unsigned short* __restrict__ Xb, int ldx,
                                       unsigned short* dstBase, int h, int k0,
                                       int tid, int wid) {
    int srow = tid >> 3;
    int scol = ((tid & 7) ^ (srow & 7)) << 3;     // inverse XOR-swizzle on global src
    const unsigned short* g = Xb + (size_t)(h*128 + srow)*ldx + k0 + scol;
    unsigned short* d = dstBase + h*8192 + wid*512;
    gload_lds16(g, d);
    gload_lds16(g + (size_t)64*ldx, d + 4096);
}

#define RD_A(BUF) do { _Pragma("unroll") for (int mf = 0; mf < 4; ++mf) { \
    fa[mf][0] = ds128(As0 + (BUF)*16384u + aRow + mf*2048u + c0); \
    fa[mf][1] = ds128(As0 + (BUF)*16384u + aRow + mf*2048u + c1); } } while (0)

#define RD_B(BUF, QN) do { _Pragma("unroll") for (int nf = 0; nf < 2; ++nf) { \
    fb[nf][0] = ds128(Bs0 + (BUF)*32768u + (QN)*16384u + bRow + nf*2048u + c0); \
    fb[nf][1] = ds128(Bs0 + (BUF)*32768u + (QN)*16384u + bRow + nf*2048u + c1); } } while (0)

#define MMA_PH(QN) do { \
    asm volatile("s_waitcnt lgkmcnt(0)" ::: "memory"); \
    __builtin_amdgcn_sched_barrier(0); \
    __builtin_amdgcn_s_setprio(1); \
    _Pragma("unroll") for (int mf = 0; mf < 4; ++mf) \
      _Pragma("unroll") for (int nf = 0; nf < 2; ++nf) \
        _Pragma("unroll") for (int ks = 0; ks < 2; ++ks) \
          acc[QN][mf][nf] = __builtin_amdgcn_mfma_f32_16x16x32_bf16( \
              fa[mf][ks], fb[nf][ks], acc[QN][mf][nf], 0, 0, 0); \
    __builtin_amdgcn_s_setprio(0); \
} while (0)

template<int MODE>   // 0: bf16(acc+bias[col]) ; 1: f32(acc)
__global__ __launch_bounds__(512, 2)
void gemm4p(const unsigned short* __restrict__ A, int lda, size_t sA,
            const unsigned short* __restrict__ Bt, int ldb, size_t sB,
            const float* __restrict__ bias,
            void* __restrict__ Cout, int ldc, size_t sC,
            int N, int K)
{
    __shared__ __align__(16) unsigned short As[2][8192];
    __shared__ __align__(16) unsigned short Bs[2][16384];
    int nbn = N >> 8;
    int bid = xcd_swz((int)blockIdx.x, (int)gridDim.x);
    int bm = bid / nbn, bn = bid % nbn;
    int bz = blockIdx.y;
    int tid = threadIdx.x;
    int lane = tid & 63;
    int wid  = tid >> 6;
    int wm = (wid >> 2) & 1;          // 2 waves in M (64 rows each)
    int wn = wid & 3;                 // 4 waves in N (32 cols each per quadrant)
    int rlo = lane & 15;
    int shi = lane >> 4;

    unsigned As0 = (unsigned)(uintptr_t)&As[0][0];
    unsigned Bs0 = (unsigned)(uintptr_t)&Bs[0][0];
    unsigned c0 = (unsigned)(((shi     ^ rlo) & 7) * 16);   // ks=0 swizzled 16B slot
    unsigned c1 = (unsigned)((((4+shi) ^ rlo) & 7) * 16);   // ks=1
    unsigned aRow = (unsigned)((wm*64 + rlo) * 128);        // byte offset in A tile
    unsigned bRow = (unsigned)((wn*32 + rlo) * 128);        // byte offset in B half

    f32x4 acc[2][4][2];
    #pragma unroll
    for (int a = 0; a < 2; a++)
        #pragma unroll
        for (int b = 0; b < 4; b++)
            #pragma unroll
            for (int c = 0; c < 2; c++)
                acc[a][b][c] = (f32x4){0.f,0.f,0.f,0.f};

    const unsigned short* Ab = A + sA*bz + (size_t)(bm*128)*lda;
    const unsigned short* Bb = Bt + sB*bz + (size_t)(bn*256)*ldb;

    // prologue: tile E {A, Bh0, Bh1} (6 loads) + tile O {A, Bh0} (4 loads);
    // vmcnt(4) drains E, leaves O's 4 in flight.
    stage1(Ab, lda, &As[0][0], 0, 0,  tid, wid);
    stage1(Bb, ldb, &Bs[0][0], 0, 0,  tid, wid);
    stage1(Bb, ldb, &Bs[0][0], 1, 0,  tid, wid);
    stage1(Ab, lda, &As[1][0], 0, 64, tid, wid);
    stage1(Bb, ldb, &Bs[1][0], 0, 64, tid, wid);
    __builtin_amdgcn_sched_barrier(0);
    asm volatile("s_waitcnt vmcnt(4)" ::: "memory");
    FENCE_BARRIER;

    short8 fa[4][2], fb[2][2];
    int nt = K >> 6;          // even, >= 4
    int nit = nt >> 1;

    for (int it = 0; it < nit; ++it) {
        int kO  = (2*it + 1) << 6;
        int kE2 = (2*it + 2 < nt) ? (2*it + 2) << 6 : 0;   // dummy k keeps ledger uniform
        int kO2 = (2*it + 3 < nt) ? (2*it + 3) << 6 : 0;

        // p1: reads A_E (8) + B_E qn0 (4); stage O.Bh1; pace; MFMA E qn0
        RD_A(0); RD_B(0, 0);
        stage1(Bb, ldb, &Bs[1][0], 1, kO, tid, wid);
        asm volatile("s_waitcnt lgkmcnt(8)" ::: "memory");
        FENCE_BARRIER; MMA_PH(0); FENCE_BARRIER;
        // p2: reads B_E qn1 (4); stage E2.A + E2.Bh0; publish O; MFMA E qn1
        RD_B(0, 1);
        stage1(Ab, lda, &As[0][0], 0, kE2, tid, wid);
        stage1(Bb, ldb, &Bs[0][0], 0, kE2, tid, wid);
        __builtin_amdgcn_sched_barrier(0);
        asm volatile("s_waitcnt vmcnt(4)" ::: "memory");
        FENCE_BARRIER; MMA_PH(1); FENCE_BARRIER;
        // p3: reads A_O (8) + B_O qn0 (4); stage E2.Bh1; pace; MFMA O qn0
        RD_A(1); RD_B(1, 0);
        stage1(Bb, ldb, &Bs[0][0], 1, kE2, tid, wid);
        asm volatile("s_waitcnt lgkmcnt(8)" ::: "memory");
        FENCE_BARRIER; MMA_PH(0); FENCE_BARRIER;
        // p4: reads B_O qn1 (4); stage O2.A + O2.Bh0; publish E2; MFMA O qn1
        RD_B(1, 1);
        stage1(Ab, lda, &As[1][0], 0, kO2, tid, wid);
        stage1(Bb, ldb, &Bs[1][0], 0, kO2, tid, wid);
        __builtin_amdgcn_sched_barrier(0);
        asm volatile("s_waitcnt vmcnt(4)" ::: "memory");
        FENCE_BARRIER; MMA_PH(1); FENCE_BARRIER;
    }

    // drain dummy-stage DMAs before LDS deallocation at wave exit
    asm volatile("s_waitcnt vmcnt(0)" ::: "memory");

    int r0 = shi << 2;
    unsigned short* Cu = (unsigned short*)Cout + sC*bz;
    float* Cf = (float*)Cout + sC*bz;
    #pragma unroll
    for (int qn = 0; qn < 2; ++qn)
        #pragma unroll
        for (int mf = 0; mf < 4; ++mf)
            #pragma unroll
            for (int nf = 0; nf < 2; ++nf) {
                int col = bn*256 + qn*128 + wn*32 + nf*16 + rlo;
                float badd = (MODE == 0) ? bias[col] : 0.f;
                #pragma unroll
                for (int r = 0; r < 4; ++r) {
                    int row = bm*128 + wm*64 + mf*16 + r0 + r;
                    float v = acc[qn][mf][nf][r];
                    if (MODE == 0) Cu[(size_t)row*ldc + col] = f2b(v + badd);
                    else           Cf[(size_t)row*ldc + col] = v;
                }
            }
}

// row softmax over 2048 fp32 scores (scaled by scl); writes bf16 probs in-place
__global__ __launch_bounds__(256)
void softmax_kernel(float* __restrict__ S, float scl) {
    int row = blockIdx.x;
    float* srow = S + (size_t)row * SEQ;
    int t = threadIdx.x;
    float4 v0 = ((const float4*)srow)[t*2];
    float4 v1 = ((const float4*)srow)[t*2+1];
    float x[8] = {v0.x*scl,v0.y*scl,v0.z*scl,v0.w*scl,v1.x*scl,v1.y*scl,v1.z*scl,v1.w*scl};
    float m = fmaxf(fmaxf(fmaxf(x[0],x[1]),fmaxf(x[2],x[3])),
                    fmaxf(fmaxf(x[4],x[5]),fmaxf(x[6],x[7])));
    #pragma unroll
    for (int off = 32; off; off >>= 1) m = fmaxf(m, __shfl_xor(m, off));
    __shared__ float redm[4], reds[4];
    int w = t >> 6;
    if ((t & 63) == 0) redm[w] = m;
    __syncthreads();
    m = fmaxf(fmaxf(redm[0], redm[1]), fmaxf(redm[2], redm[3]));
    float e[8]; float s = 0.f;
    #pragma unroll
    for (int i = 0; i < 8; i++) { e[i] = __expf(x[i] - m); s += e[i]; }
    #pragma unroll
    for (int off = 32; off; off >>= 1) s += __shfl_xor(s, off);
    if ((t & 63) == 0) reds[w] = s;
    __syncthreads();
    float inv = 1.0f / (reds[0]+reds[1]+reds[2]+reds[3]);
    union { unsigned short u[8]; uint4 v; } r;
    #pragma unroll
    for (int i = 0; i < 8; i++) r.u[i] = f2b(e[i] * inv);
    ((uint4*)srow)[t] = r.v;
}

extern "C" void kernel_launch(void* const* d_in, const int* in_sizes, int n_in,
                              void* d_out, int out_size, void* d_ws, size_t ws_size,
                              hipStream_t stream)
{
    (void)in_sizes; (void)n_in; (void)out_size;
    const float* x  = (const float*)d_in[0];
    const float* Wq = (const float*)d_in[1];
    const float* bq = (const float*)d_in[2];
    const float* Wk = (const float*)d_in[3];
    const float* bk = (const float*)d_in[4];
    const float* Wv = (const float*)d_in[5];
    const float* bv = (const float*)d_in[6];
    float* out = (float*)d_out;

    unsigned short* qkv = (unsigned short*)d_ws;                    // [8192][3072]
    unsigned short* vt  = qkv + (size_t)MTOT*QKVN;                  // [4][1024][2048]
    float* biasc = (float*)(vt + (size_t)NB*DIM*SEQ);               // [3072]
    char* ovl = (char*)biasc + 65536;
    unsigned short* xb    = (unsigned short*)ovl;                   // [8192][1024]
    unsigned short* wqkvt = xb + (size_t)MTOT*DIM;                  // [3072][1024]
    float* scores = (float*)ovl;                                    // [bpp][2048][2048]

    size_t base = (size_t)MTOT*QKVN*2 + (size_t)NB*DIM*SEQ*2 + 65536;
    int bpp = 1;
    if (base + 4*(size_t)SEQ*SEQ*4 <= ws_size) bpp = 4;
    else if (base + 2*(size_t)SEQ*SEQ*4 <= ws_size) bpp = 2;

    cast_kernel<<<MTOT*DIM/8/256, 256, 0, stream>>>(x, xb, MTOT*DIM/8);
    transpose_cast_f32<<<256, 256, 0, stream>>>(Wq, wqkvt,             DIM, DIM);
    transpose_cast_f32<<<256, 256, 0, stream>>>(Wk, wqkvt + DIM*DIM,   DIM, DIM);
    transpose_cast_f32<<<256, 256, 0, stream>>>(Wv, wqkvt + 2*DIM*DIM, DIM, DIM);
    bias_concat<<<QKVN/256, 256, 0, stream>>>(bq, bk, bv, biasc);

    // fused QKV projection: [8192,1024] @ [3072,1024]^T, grid 64x12=768 (3.0 rounds)
    gemm4p<0><<<dim3((MTOT/128)*(QKVN/256)), 512, 0, stream>>>(
        xb, DIM, 0, wqkvt, DIM, 0, biasc, qkv, QKVN, 0, QKVN, DIM);

    transpose_b16<<<dim3((SEQ/64)*(DIM/64), NB), 256, 0, stream>>>(
        qkv + 2*DIM, (size_t)SEQ*QKVN, QKVN, vt, (size_t)DIM*SEQ, SEQ, DIM/64);

    const float scl = 1.0f / 32.0f;   // 1/sqrt(1024), folded into softmax
    for (int p = 0; p < NB; p += bpp) {
        const unsigned short* qp = qkv + (size_t)p*SEQ*QKVN;
        // scores: grid 16x8=128 per batch (x), bpp batches (y) -> 512 blocks (2.0 rounds)
        gemm4p<1><<<dim3((SEQ/128)*(SEQ/256), bpp), 512, 0, stream>>>(
            qp,       QKVN, (size_t)SEQ*QKVN,
            qp + DIM, QKVN, (size_t)SEQ*QKVN,
            nullptr, scores, SEQ, (size_t)SEQ*SEQ, SEQ, DIM);
        softmax_kernel<<<bpp*SEQ, 256, 0, stream>>>(scores, scl);
        // PV: grid 16x4=64 per batch -> 256 blocks (1.0 round), pipelined schedule
        gemm4p<1><<<dim3((SEQ/128)*(DIM/256), bpp), 512, 0, stream>>>(
            (const unsigned short*)scores, 2*SEQ, (size_t)SEQ*2*SEQ,
            vt + (size_t)p*DIM*SEQ,        SEQ,   (size_t)DIM*SEQ,
            nullptr, out + (size_t)p*SEQ*DIM, DIM, (size_t)SEQ*DIM, DIM, SEQ);
    }
}

// Round 11
// 189.017 us; speedup vs baseline: 1.5258x; 1.0040x over previous
//
#include <hip/hip_runtime.h>
#include <stdint.h>

#define SEQ 2048
#define DIM 1024
#define NB 4
#define MTOT (NB*SEQ)
#define QKVN (3*DIM)

typedef __attribute__((ext_vector_type(8))) short short8;
typedef __attribute__((ext_vector_type(4))) float f32x4;

__device__ __forceinline__ unsigned short f2b(float f) {
    union { float f; unsigned int u; } v; v.f = f;
    return (unsigned short)((v.u + 0x7FFFu + ((v.u >> 16) & 1u)) >> 16);
}

__device__ __forceinline__ void gload_lds16(const unsigned short* g, unsigned short* l) {
    __builtin_amdgcn_global_load_lds(
        (const __attribute__((address_space(1))) void*)g,
        (__attribute__((address_space(3))) void*)l, 16, 0, 0);
}

// inline-asm LDS read: invisible to backend waitcnt insertion; dependency on the
// LDS-DMA is managed ONLY by our counted vmcnt/lgkmcnt ledger.
__device__ __forceinline__ short8 ds128(unsigned addr) {
    short8 r;
    asm volatile("ds_read_b128 %0, %1" : "=v"(r) : "v"(addr));
    return r;
}

#define FENCE_BARRIER do { asm volatile("" ::: "memory"); \
    __builtin_amdgcn_s_barrier(); asm volatile("" ::: "memory"); } while (0)

__device__ __forceinline__ int xcd_swz(int bid, int nwg) {
    if (nwg & 7) return bid;
    return (bid & 7) * (nwg >> 3) + (bid >> 3);
}

// ---------------- small memory-shape kernels ----------------

__global__ __launch_bounds__(256)
void cast_kernel(const float* __restrict__ in, unsigned short* __restrict__ out, int nchunk) {
    int i = blockIdx.x * 256 + threadIdx.x;
    if (i >= nchunk) return;
    float4 a = ((const float4*)in)[i*2];
    float4 b = ((const float4*)in)[i*2+1];
    union { unsigned short u[8]; uint4 v; } r;
    r.u[0]=f2b(a.x); r.u[1]=f2b(a.y); r.u[2]=f2b(a.z); r.u[3]=f2b(a.w);
    r.u[4]=f2b(b.x); r.u[5]=f2b(b.y); r.u[6]=f2b(b.z); r.u[7]=f2b(b.w);
    ((uint4*)out)[i] = r.v;
}

__global__ __launch_bounds__(256)
void transpose_cast_f32(const float* __restrict__ in, unsigned short* __restrict__ out, int R, int C) {
    __shared__ unsigned short tile[64][66];
    int tpc = C >> 6;
    int tr = (blockIdx.x / tpc) << 6;
    int tc = (blockIdx.x % tpc) << 6;
    int t = threadIdx.x;
    #pragma unroll
    for (int i = 0; i < 16; i++) {
        int idx = t + i*256;
        int r = idx >> 6, c = idx & 63;
        tile[r][c] = f2b(in[(size_t)(tr + r)*C + tc + c]);
    }
    __syncthreads();
    #pragma unroll
    for (int i = 0; i < 16; i++) {
        int idx = t + i*256;
        int r = idx >> 6, c = idx & 63;
        out[(size_t)(tc + r)*R + tr + c] = tile[c][r];
    }
}

__global__ __launch_bounds__(256)
void transpose_b16(const unsigned short* __restrict__ in0, size_t sIn, int ldin,
                   unsigned short* __restrict__ out0, size_t sOut, int ldout, int tpc) {
    const unsigned short* in = in0 + sIn * blockIdx.y;
    unsigned short* out = out0 + sOut * blockIdx.y;
    __shared__ unsigned short tile[64][66];
    int tr = ((int)blockIdx.x / tpc) << 6;
    int tc = ((int)blockIdx.x % tpc) << 6;
    int t = threadIdx.x;
    #pragma unroll
    for (int i = 0; i < 16; i++) {
        int idx = t + i*256;
        int r = idx >> 6, c = idx & 63;
        tile[r][c] = in[(size_t)(tr + r)*ldin + tc + c];
    }
    __syncthreads();
    #pragma unroll
    for (int i = 0; i < 16; i++) {
        int idx = t + i*256;
        int r = idx >> 6, c = idx & 63;
        out[(size_t)(tc + r)*ldout + tr + c] = tile[c][r];
    }
}

__global__ __launch_bounds__(256)
void bias_concat(const float* __restrict__ bq, const float* __restrict__ bk,
                 const float* __restrict__ bv, float* __restrict__ o) {
    int i = blockIdx.x*256 + threadIdx.x;
    float v = (i < DIM) ? bq[i] : ((i < 2*DIM) ? bk[i-DIM] : bv[i-2*DIM]);
    o[i] = v;
}

// -------- 128x256 4-phase pipelined GEMM (exact-grid tiles) --------
// 8 waves (2M x 4N), BK=64, 2 K-tiles/iter (E=buf0, O=buf1). Per-wave 64x64,
// acc = 16 f32x4 (64 AGPR). Per phase: one qn-quadrant (128 cols) x one K-step
// = 16 MFMA. A-frags read once per K-tile (phase qn0) and held across qn1.
// LDS 96KB: As[2][128x64] 32KB + Bs[2][256x64] 64KB. XOR-swizzled via
// pre-swizzled global source (stage) + swizzled ds_read addr.
// Stage slots: p1 O.Bh1 | p2 E2.A + E2.Bh0, vmcnt(4) (publish O) |
//              p3 E2.Bh1 | p4 O2.A + O2.Bh0, vmcnt(4) (publish E2).
// Hazards: B-half h == qn-quadrant h; each staged half's last reader finished
// >=1 barrier before the stage issues (A@qn0-phase, Bh0@qn0, Bh1@qn1). Ledger:
// prologue 10 loads -> vmcnt(4); steady-state 8 in flight at publishes.

__device__ __forceinline__ void stage1(const unsigned short* __restrict__ Xb, int ldx,
                                       unsigned short* dstBase, int h, int k0,
                                       int tid, int wid) {
    int srow = tid >> 3;
    int scol = ((tid & 7) ^ (srow & 7)) << 3;     // inverse XOR-swizzle on global src
    const unsigned short* g = Xb + (size_t)(h*128 + srow)*ldx + k0 + scol;
    unsigned short* d = dstBase + h*8192 + wid*512;
    gload_lds16(g, d);
    gload_lds16(g + (size_t)64*ldx, d + 4096);
}

#define RD_A(BUF) do { _Pragma("unroll") for (int mf = 0; mf < 4; ++mf) { \
    fa[mf][0] = ds128(As0 + (BUF)*16384u + aRow + mf*2048u + c0); \
    fa[mf][1] = ds128(As0 + (BUF)*16384u + aRow + mf*2048u + c1); } } while (0)

#define RD_B(BUF, QN) do { _Pragma("unroll") for (int nf = 0; nf < 2; ++nf) { \
    fb[nf][0] = ds128(Bs0 + (BUF)*32768u + (QN)*16384u + bRow + nf*2048u + c0); \
    fb[nf][1] = ds128(Bs0 + (BUF)*32768u + (QN)*16384u + bRow + nf*2048u + c1); } } while (0)

#define MMA_PH(QN) do { \
    asm volatile("s_waitcnt lgkmcnt(0)" ::: "memory"); \
    __builtin_amdgcn_sched_barrier(0); \
    __builtin_amdgcn_s_setprio(1); \
    _Pragma("unroll") for (int mf = 0; mf < 4; ++mf) \
      _Pragma("unroll") for (int nf = 0; nf < 2; ++nf) \
        _Pragma("unroll") for (int ks = 0; ks < 2; ++ks) \
          acc[QN][mf][nf] = __builtin_amdgcn_mfma_f32_16x16x32_bf16( \
              fa[mf][ks], fb[nf][ks], acc[QN][mf][nf], 0, 0, 0); \
    __builtin_amdgcn_s_setprio(0); \
} while (0)

template<int MODE>   // 0: bf16(acc+bias[col]) ; 1: f32(acc)
__global__ __launch_bounds__(512, 2)
void gemm4p(const unsigned short* __restrict__ A, int lda, size_t sA,
            const unsigned short* __restrict__ Bt, int ldb, size_t sB,
            const float* __restrict__ bias,
            void* __restrict__ Cout, int ldc, size_t sC,
            int N, int K)
{
    __shared__ __align__(16) unsigned short As[2][8192];
    __shared__ __align__(16) unsigned short Bs[2][16384];
    int nbn = N >> 8;
    int bid = xcd_swz((int)blockIdx.x, (int)gridDim.x);
    int bm = bid / nbn, bn = bid % nbn;
    int bz = blockIdx.y;
    int tid = threadIdx.x;
    int lane = tid & 63;
    int wid  = tid >> 6;
    int wm = (wid >> 2) & 1;          // 2 waves in M (64 rows each)
    int wn = wid & 3;                 // 4 waves in N (32 cols each per quadrant)
    int rlo = lane & 15;
    int shi = lane >> 4;

    unsigned As0 = (unsigned)(uintptr_t)&As[0][0];
    unsigned Bs0 = (unsigned)(uintptr_t)&Bs[0][0];
    unsigned c0 = (unsigned)(((shi     ^ rlo) & 7) * 16);   // ks=0 swizzled 16B slot
    unsigned c1 = (unsigned)((((4+shi) ^ rlo) & 7) * 16);   // ks=1
    unsigned aRow = (unsigned)((wm*64 + rlo) * 128);        // byte offset in A tile
    unsigned bRow = (unsigned)((wn*32 + rlo) * 128);        // byte offset in B half

    f32x4 acc[2][4][2];
    #pragma unroll
    for (int a = 0; a < 2; a++)
        #pragma unroll
        for (int b = 0; b < 4; b++)
            #pragma unroll
            for (int c = 0; c < 2; c++)
                acc[a][b][c] = (f32x4){0.f,0.f,0.f,0.f};

    const unsigned short* Ab = A + sA*bz + (size_t)(bm*128)*lda;
    const unsigned short* Bb = Bt + sB*bz + (size_t)(bn*256)*ldb;

    // prologue: tile E {A, Bh0, Bh1} (6 loads) + tile O {A, Bh0} (4 loads);
    // vmcnt(4) drains E, leaves O's 4 in flight.
    stage1(Ab, lda, &As[0][0], 0, 0,  tid, wid);
    stage1(Bb, ldb, &Bs[0][0], 0, 0,  tid, wid);
    stage1(Bb, ldb, &Bs[0][0], 1, 0,  tid, wid);
    stage1(Ab, lda, &As[1][0], 0, 64, tid, wid);
    stage1(Bb, ldb, &Bs[1][0], 0, 64, tid, wid);
    __builtin_amdgcn_sched_barrier(0);
    asm volatile("s_waitcnt vmcnt(4)" ::: "memory");
    FENCE_BARRIER;

    short8 fa[4][2], fb[2][2];
    int nt = K >> 6;          // even, >= 4
    int nit = nt >> 1;

    for (int it = 0; it < nit; ++it) {
        int kO  = (2*it + 1) << 6;
        int kE2 = (2*it + 2 < nt) ? (2*it + 2) << 6 : 0;   // dummy k keeps ledger uniform
        int kO2 = (2*it + 3 < nt) ? (2*it + 3) << 6 : 0;

        // p1: reads A_E (8) + B_E qn0 (4); stage O.Bh1; pace; MFMA E qn0
        RD_A(0); RD_B(0, 0);
        stage1(Bb, ldb, &Bs[1][0], 1, kO, tid, wid);
        asm volatile("s_waitcnt lgkmcnt(8)" ::: "memory");
        FENCE_BARRIER; MMA_PH(0); FENCE_BARRIER;
        // p2: reads B_E qn1 (4); stage E2.A + E2.Bh0; publish O; MFMA E qn1
        RD_B(0, 1);
        stage1(Ab, lda, &As[0][0], 0, kE2, tid, wid);
        stage1(Bb, ldb, &Bs[0][0], 0, kE2, tid, wid);
        __builtin_amdgcn_sched_barrier(0);
        asm volatile("s_waitcnt vmcnt(4)" ::: "memory");
        FENCE_BARRIER; MMA_PH(1); FENCE_BARRIER;
        // p3: reads A_O (8) + B_O qn0 (4); stage E2.Bh1; pace; MFMA O qn0
        RD_A(1); RD_B(1, 0);
        stage1(Bb, ldb, &Bs[0][0], 1, kE2, tid, wid);
        asm volatile("s_waitcnt lgkmcnt(8)" ::: "memory");
        FENCE_BARRIER; MMA_PH(0); FENCE_BARRIER;
        // p4: reads B_O qn1 (4); stage O2.A + O2.Bh0; publish E2; MFMA O qn1
        RD_B(1, 1);
        stage1(Ab, lda, &As[1][0], 0, kO2, tid, wid);
        stage1(Bb, ldb, &Bs[1][0], 0, kO2, tid, wid);
        __builtin_amdgcn_sched_barrier(0);
        asm volatile("s_waitcnt vmcnt(4)" ::: "memory");
        FENCE_BARRIER; MMA_PH(1); FENCE_BARRIER;
    }

    // drain dummy-stage DMAs before LDS deallocation at wave exit
    asm volatile("s_waitcnt vmcnt(0)" ::: "memory");

    int r0 = shi << 2;
    unsigned short* Cu = (unsigned short*)Cout + sC*bz;
    float* Cf = (float*)Cout + sC*bz;
    #pragma unroll
    for (int qn = 0; qn < 2; ++qn)
        #pragma unroll
        for (int mf = 0; mf < 4; ++mf)
            #pragma unroll
            for (int nf = 0; nf < 2; ++nf) {
                int col = bn*256 + qn*128 + wn*32 + nf*16 + rlo;
                float badd = (MODE == 0) ? bias[col] : 0.f;
                #pragma unroll
                for (int r = 0; r < 4; ++r) {
                    int row = bm*128 + wm*64 + mf*16 + r0 + r;
                    float v = acc[qn][mf][nf][r];
                    if (MODE == 0) Cu[(size_t)row*ldc + col] = f2b(v + badd);
                    else           Cf[(size_t)row*ldc + col] = v;
                }
            }
}

// row softmax over 2048 fp32 scores (scaled by scl); writes bf16 probs in-place
__global__ __launch_bounds__(256)
void softmax_kernel(float* __restrict__ S, float scl) {
    int row = blockIdx.x;
    float* srow = S + (size_t)row * SEQ;
    int t = threadIdx.x;
    float4 v0 = ((const float4*)srow)[t*2];
    float4 v1 = ((const float4*)srow)[t*2+1];
    float x[8] = {v0.x*scl,v0.y*scl,v0.z*scl,v0.w*scl,v1.x*scl,v1.y*scl,v1.z*scl,v1.w*scl};
    float m = fmaxf(fmaxf(fmaxf(x[0],x[1]),fmaxf(x[2],x[3])),
                    fmaxf(fmaxf(x[4],x[5]),fmaxf(x[6],x[7])));
    #pragma unroll
    for (int off = 32; off; off >>= 1) m = fmaxf(m, __shfl_xor(m, off));
    __shared__ float redm[4], reds[4];
    int w = t >> 6;
    if ((t & 63) == 0) redm[w] = m;
    __syncthreads();
    m = fmaxf(fmaxf(redm[0], redm[1]), fmaxf(redm[2], redm[3]));
    float e[8]; float s = 0.f;
    #pragma unroll
    for (int i = 0; i < 8; i++) { e[i] = __expf(x[i] - m); s += e[i]; }
    #pragma unroll
    for (int off = 32; off; off >>= 1) s += __shfl_xor(s, off);
    if ((t & 63) == 0) reds[w] = s;
    __syncthreads();
    float inv = 1.0f / (reds[0]+reds[1]+reds[2]+reds[3]);
    union { unsigned short u[8]; uint4 v; } r;
    #pragma unroll
    for (int i = 0; i < 8; i++) r.u[i] = f2b(e[i] * inv);
    ((uint4*)srow)[t] = r.v;
}

extern "C" void kernel_launch(void* const* d_in, const int* in_sizes, int n_in,
                              void* d_out, int out_size, void* d_ws, size_t ws_size,
                              hipStream_t stream)
{
    (void)in_sizes; (void)n_in; (void)out_size;
    const float* x  = (const float*)d_in[0];
    const float* Wq = (const float*)d_in[1];
    const float* bq = (const float*)d_in[2];
    const float* Wk = (const float*)d_in[3];
    const float* bk = (const float*)d_in[4];
    const float* Wv = (const float*)d_in[5];
    const float* bv = (const float*)d_in[6];
    float* out = (float*)d_out;

    unsigned short* qkv = (unsigned short*)d_ws;                    // [8192][3072]
    unsigned short* vt  = qkv + (size_t)MTOT*QKVN;                  // [4][1024][2048]
    float* biasc = (float*)(vt + (size_t)NB*DIM*SEQ);               // [3072]
    char* ovl = (char*)biasc + 65536;
    unsigned short* xb    = (unsigned short*)ovl;                   // [8192][1024]
    unsigned short* wqkvt = xb + (size_t)MTOT*DIM;                  // [3072][1024]
    float* scores = (float*)ovl;                                    // [bpp][2048][2048]

    size_t base = (size_t)MTOT*QKVN*2 + (size_t)NB*DIM*SEQ*2 + 65536;
    int bpp = 1;
    if (base + 4*(size_t)SEQ*SEQ*4 <= ws_size) bpp = 4;
    else if (base + 2*(size_t)SEQ*SEQ*4 <= ws_size) bpp = 2;

    cast_kernel<<<MTOT*DIM/8/256, 256, 0, stream>>>(x, xb, MTOT*DIM/8);
    transpose_cast_f32<<<256, 256, 0, stream>>>(Wq, wqkvt,             DIM, DIM);
    transpose_cast_f32<<<256, 256, 0, stream>>>(Wk, wqkvt + DIM*DIM,   DIM, DIM);
    transpose_cast_f32<<<256, 256, 0, stream>>>(Wv, wqkvt + 2*DIM*DIM, DIM, DIM);
    bias_concat<<<QKVN/256, 256, 0, stream>>>(bq, bk, bv, biasc);

    // fused QKV projection: [8192,1024] @ [3072,1024]^T, grid 64x12=768 (3.0 rounds)
    gemm4p<0><<<dim3((MTOT/128)*(QKVN/256)), 512, 0, stream>>>(
        xb, DIM, 0, wqkvt, DIM, 0, biasc, qkv, QKVN, 0, QKVN, DIM);

    transpose_b16<<<dim3((SEQ/64)*(DIM/64), NB), 256, 0, stream>>>(
        qkv + 2*DIM, (size_t)SEQ*QKVN, QKVN, vt, (size_t)DIM*SEQ, SEQ, DIM/64);

    const float scl = 1.0f / 32.0f;   // 1/sqrt(1024), folded into softmax
    for (int p = 0; p < NB; p += bpp) {
        const unsigned short* qp = qkv + (size_t)p*SEQ*QKVN;
        // scores: grid 16x8=128 per batch (x), bpp batches (y) -> 512 blocks (2.0 rounds)
        gemm4p<1><<<dim3((SEQ/128)*(SEQ/256), bpp), 512, 0, stream>>>(
            qp,       QKVN, (size_t)SEQ*QKVN,
            qp + DIM, QKVN, (size_t)SEQ*QKVN,
            nullptr, scores, SEQ, (size_t)SEQ*SEQ, SEQ, DIM);
        softmax_kernel<<<bpp*SEQ, 256, 0, stream>>>(scores, scl);
        // PV: grid 16x4=64 per batch -> 256 blocks (1.0 round), pipelined schedule
        gemm4p<1><<<dim3((SEQ/128)*(DIM/256), bpp), 512, 0, stream>>>(
            (const unsigned short*)scores, 2*SEQ, (size_t)SEQ*2*SEQ,
            vt + (size_t)p*DIM*SEQ,        SEQ,   (size_t)DIM*SEQ,
            nullptr, out + (size_t)p*SEQ*DIM, DIM, (size_t)SEQ*DIM, DIM, SEQ);
    }
}